// Round 6
// baseline (155.149 us; speedup 1.0000x reference)
//
#include <hip/hip_runtime.h>
#include <hip/hip_bf16.h>

// Sizes (fixed by the problem)
#define NS   4096      // samples
#define NV   256       // variables/channels
#define NHID 64        // hidden
#define K2F  2.8853900817779268f   // 2*log2(e)

typedef short s8v __attribute__((ext_vector_type(8)));
typedef float f4v __attribute__((ext_vector_type(4)));

__device__ __forceinline__ unsigned short f2bf(float x) {
    __hip_bfloat16 h = __float2bfloat16(x);
    return *reinterpret_cast<unsigned short*>(&h);
}

// ---- prep: W2t[col][k] = adj[k,c] * w_in[c, k-(k>c), h],  col = c*64+h ----
__global__ __launch_bounds__(256) void k_prep_w2t(const float* __restrict__ adj,
                                                  const float* __restrict__ w_in,
                                                  unsigned short* __restrict__ W2t) {
    __shared__ float t[64][65];
    int c  = blockIdx.x >> 2;
    int k0 = (blockIdx.x & 3) * 64;
    int tid = threadIdx.x;
#pragma unroll
    for (int i = 0; i < 16; ++i) {
        int lin = i * 256 + tid;
        int kr = lin >> 6, h = lin & 63;
        int k = k0 + kr;
        float v = 0.0f;
        if (k != c) {
            int m = k - (k > c ? 1 : 0);
            v = adj[k * NV + c] * w_in[((size_t)c * 255 + m) * 64 + h];
        }
        t[kr][h] = v;
    }
    __syncthreads();
#pragma unroll
    for (int i = 0; i < 16; ++i) {
        int lin = i * 256 + tid;
        int h = lin >> 6, kr = lin & 63;
        W2t[((size_t)(c * 64 + h)) * NV + k0 + kr] = f2bf(t[kr][h]);
    }
}

// ---- prep (fused): data->bf16, out0=adj copy, g2/BO, bi2 ----
__global__ __launch_bounds__(256) void k_prep_small(
        const float* __restrict__ data, unsigned short* __restrict__ dataB,
        const float* __restrict__ adj,  float* __restrict__ out0,
        const float* __restrict__ neurons, const float* __restrict__ w_out,
        const float* __restrict__ b_out, float* __restrict__ g2, float* __restrict__ BO,
        const float* __restrict__ b_in, float* __restrict__ bi2)
{
    const int b = blockIdx.x, tid = threadIdx.x;
    if (b < 1024) {                       // data f32 -> bf16 (262144 float4)
        int i = b * 256 + tid;
        float4 v = reinterpret_cast<const float4*>(data)[i];
        ushort4 o = make_ushort4(f2bf(v.x), f2bf(v.y), f2bf(v.z), f2bf(v.w));
        reinterpret_cast<ushort4*>(dataB)[i] = o;
    } else if (b < 1088) {                // out0 = adj (16384 float4)
        int i = (b - 1024) * 256 + tid;
        reinterpret_cast<float4*>(out0)[i] = reinterpret_cast<const float4*>(adj)[i];
    } else if (b < 1152) {                // g2[j] = 2*neurons[h,c]*w_out[j]; BO[c]=b_out[c]+sum_h g
        int j = (b - 1088) * 256 + tid;
        int c = j >> 6, h = j & 63;
        float gv = neurons[h * NV + c] * w_out[j];
        g2[j] = 2.0f * gv;
        float s = gv;
        s += __shfl_xor(s, 1);  s += __shfl_xor(s, 2);  s += __shfl_xor(s, 4);
        s += __shfl_xor(s, 8);  s += __shfl_xor(s, 16); s += __shfl_xor(s, 32);
        if ((tid & 63) == 0) BO[c] = b_out[c] + s;
    } else {                              // bi2 = K2 * b_in (4096 float4)
        int i = (b - 1152) * 256 + tid;
        float4 v = reinterpret_cast<const float4*>(b_in)[i];
        v.x *= K2F; v.y *= K2F; v.z *= K2F; v.w *= K2F;
        reinterpret_cast<float4*>(bi2)[i] = v;
    }
}

// ---- main: all-register streaming GEMM + fused tanh/gate/reduce.
// Block = 4 waves; wave = 32 A-rows (full K=256 resident, 64 VGPR); all 4
// waves share the SAME 16 channels (L1 reuse of the B stream), lockstepped by
// a raw s_barrier per channel. B streams global->reg.
// Window 4 slots / distance 2: 8 steps per channel, 8 % 4 == 0, so slot
// phase realigns at channel boundaries (the v5 bug was window 3: 8 % 3 != 0).
// Swapped MFMA: D rows = h, D cols = m => h-sum is in-lane + 2 shfl.
__global__ __launch_bounds__(256, 2) void k_gemm_fused(
        const unsigned short* __restrict__ dataB,   // [4096][256] bf16
        const unsigned short* __restrict__ W2t,     // [16384][256] bf16
        const float* __restrict__ g2,               // [16384] 2*g
        const float* __restrict__ bi2,              // [16384] K2*b_in
        const float* __restrict__ BO,               // [256]  b_out + sum_h g
        float* __restrict__ out1)                   // [4096][256]
{
    __shared__ float obuf[4][32][20];               // [wave][row][ch], pad 20 for b128 align
    const int tid  = threadIdx.x;
    const int w    = tid >> 6, lane = tid & 63;
    const int lq   = lane >> 4, lr = lane & 15;
    // grid 512 = 8 xcd-groups x 64; each XCD gets 2 channel-groups (B slice
    // ~1MB) x 32 m-strips (A 2MB) -> L2-resident working set.
    const int bid    = (int)blockIdx.x;
    const int xcd    = bid & 7, idx = bid >> 3;
    const int chgrp  = xcd * 2 + (idx >> 5);
    const int mstrip = idx & 31;
    const int m0     = mstrip * 128 + w * 32;
    const int cbase  = chgrp * 16;

    const s8v* Ab = (const s8v*)dataB;              // 16B units: row*32 + ks*4 + lq
    const s8v* Bb = (const s8v*)W2t;                // 16B units: col*32 + ks*4 + lq

    // A fragments, full K resident
    s8v a[2][8];
#pragma unroll
    for (int mi = 0; mi < 2; ++mi)
#pragma unroll
        for (int ks = 0; ks < 8; ++ks)
            a[mi][ks] = Ab[(unsigned)(m0 + mi * 16 + lr) * 32u + ks * 4 + lq];

    // B window: 4 slots, prefetch distance 2. Preload steps 0,1 of channel 0.
    s8v win[4][4];
#pragma unroll
    for (int j = 0; j < 2; ++j)
#pragma unroll
        for (int hf = 0; hf < 4; ++hf)
            win[j][hf] = Bb[(unsigned)(cbase * 64 + hf * 16 + lr) * 32u + j * 4 + lq];

    for (int ch = 0; ch < 16; ++ch) {
        const int c = cbase + ch;
        __builtin_amdgcn_s_barrier();               // keep 4 waves' B-streams L1-aligned

        float4 g2v[4], bi2v[4];
#pragma unroll
        for (int hf = 0; hf < 4; ++hf) {
            g2v[hf]  = *(const float4*)&g2 [c * 64 + hf * 16 + lq * 4];
            bi2v[hf] = *(const float4*)&bi2[c * 64 + hf * 16 + lq * 4];
        }
        const float BOv = BO[c];

        f4v acc[2][4];
#pragma unroll
        for (int kk = 0; kk < 8; ++kk) {
            // prefetch step kk+2 into slot (kk+2)&3 (wraps into next channel;
            // for the last channel the overrun reads land in ws scratch after
            // W2t and are never consumed)
            {
                const int st = kk + 2;
                const int c2 = c + (st >> 3);
                const int k2 = st & 7;
#pragma unroll
                for (int hf = 0; hf < 4; ++hf)
                    win[st & 3][hf] =
                        Bb[(unsigned)(c2 * 64 + hf * 16 + lr) * 32u + k2 * 4 + lq];
            }
            // consume slot kk&3 (8 % 4 == 0 -> phase-aligned across channels)
#pragma unroll
            for (int mi = 0; mi < 2; ++mi)
#pragma unroll
                for (int hf = 0; hf < 4; ++hf) {
                    f4v cin = (kk == 0) ? (f4v){0.f, 0.f, 0.f, 0.f} : acc[mi][hf];
                    acc[mi][hf] = __builtin_amdgcn_mfma_f32_16x16x32_bf16(
                        win[kk & 3][hf], a[mi][kk], cin, 0, 0, 0);
                }
        }

        // Epilogue: per lane h = hf*16 + lq*4 + r ; m-local col = lr
        float s0, s1;
#define EPI_TERM(T, GC, BC, RR)                                                \
        { float mm = __builtin_fmaf(acc[mi][hf][RR], K2F, (BC));               \
          float e  = __builtin_amdgcn_exp2f(mm);                               \
          (T) = __builtin_fmaf((GC), __builtin_amdgcn_rcpf(e + 1.0f), (T)); }
#define EPI_MI(T)                                                              \
        { float t = 0.f;                                                       \
          _Pragma("unroll")                                                    \
          for (int hf = 0; hf < 4; ++hf) {                                     \
              EPI_TERM(t, g2v[hf].x, bi2v[hf].x, 0);                           \
              EPI_TERM(t, g2v[hf].y, bi2v[hf].y, 1);                           \
              EPI_TERM(t, g2v[hf].z, bi2v[hf].z, 2);                           \
              EPI_TERM(t, g2v[hf].w, bi2v[hf].w, 3);                           \
          }                                                                    \
          t += __shfl_xor(t, 16);                                              \
          t += __shfl_xor(t, 32);                                              \
          (T) = t; }
        { const int mi = 0; EPI_MI(s0); }
        { const int mi = 1; EPI_MI(s1); }
#undef EPI_MI
#undef EPI_TERM
        if (lane < 32)
            obuf[w][lane][ch] = BOv - (lane < 16 ? s0 : s1);
    }

    // Coalesced store: row = lane>>1, 8 channels per lane -> 2x dwordx4
    const int row = lane >> 1, cof = (lane & 1) * 8;
    float4 v0 = *(const float4*)&obuf[w][row][cof];
    float4 v1 = *(const float4*)&obuf[w][row][cof + 4];
    float* dst = &out1[(size_t)(m0 + row) * NV + cbase + cof];
    *(float4*)dst       = v0;
    *(float4*)(dst + 4) = v1;
}

extern "C" void kernel_launch(void* const* d_in, const int* in_sizes, int n_in,
                              void* d_out, int out_size, void* d_ws, size_t ws_size,
                              hipStream_t stream) {
    const float* data    = (const float*)d_in[0];
    const float* adj     = (const float*)d_in[1];
    const float* neurons = (const float*)d_in[2];
    const float* w_in    = (const float*)d_in[3];
    const float* b_in    = (const float*)d_in[4];
    const float* w_out   = (const float*)d_in[5];
    const float* b_out   = (const float*)d_in[6];

    float* out0 = (float*)d_out;
    float* out1 = out0 + NV * NV;

    unsigned short* dataB = (unsigned short*)d_ws;                       // 2 MiB
    unsigned short* W2t   = (unsigned short*)((char*)d_ws + 2097152);    // 8 MiB
    float*          g2    = (float*)((char*)d_ws + 10485760);            // 64 KiB
    float*          bi2   = (float*)((char*)d_ws + 10551296);            // 64 KiB
    float*          BO    = (float*)((char*)d_ws + 10616832);            // 1 KiB

    hipLaunchKernelGGL(k_prep_w2t,   dim3(1024), dim3(256), 0, stream, adj, w_in, W2t);
    hipLaunchKernelGGL(k_prep_small, dim3(1168), dim3(256), 0, stream,
                       data, dataB, adj, out0, neurons, w_out, b_out, g2, BO, b_in, bi2);
    hipLaunchKernelGGL(k_gemm_fused, dim3(512), dim3(256), 0, stream,
                       dataB, W2t, g2, bi2, BO, out1);
}

// Round 7
// 104.656 us; speedup vs baseline: 1.4825x; 1.4825x over previous
//
#include <hip/hip_runtime.h>
#include <hip/hip_bf16.h>

// Sizes (fixed by the problem)
#define NS   4096      // samples
#define NV   256       // variables/channels
#define NHID 64        // hidden
#define K2F  2.8853900817779268f   // 2*log2(e)

typedef short s8v __attribute__((ext_vector_type(8)));
typedef float f4v __attribute__((ext_vector_type(4)));

__device__ __forceinline__ unsigned short f2bf(float x) {
    __hip_bfloat16 h = __float2bfloat16(x);
    return *reinterpret_cast<unsigned short*>(&h);
}

// ---- prep: W2t[col][k] = adj[k,c] * w_in[c, k-(k>c), h],  col = c*64+h ----
__global__ __launch_bounds__(256) void k_prep_w2t(const float* __restrict__ adj,
                                                  const float* __restrict__ w_in,
                                                  unsigned short* __restrict__ W2t) {
    __shared__ float t[64][65];
    int c  = blockIdx.x >> 2;
    int k0 = (blockIdx.x & 3) * 64;
    int tid = threadIdx.x;
#pragma unroll
    for (int i = 0; i < 16; ++i) {
        int lin = i * 256 + tid;
        int kr = lin >> 6, h = lin & 63;
        int k = k0 + kr;
        float v = 0.0f;
        if (k != c) {
            int m = k - (k > c ? 1 : 0);
            v = adj[k * NV + c] * w_in[((size_t)c * 255 + m) * 64 + h];
        }
        t[kr][h] = v;
    }
    __syncthreads();
#pragma unroll
    for (int i = 0; i < 16; ++i) {
        int lin = i * 256 + tid;
        int h = lin >> 6, kr = lin & 63;
        W2t[((size_t)(c * 64 + h)) * NV + k0 + kr] = f2bf(t[kr][h]);
    }
}

// ---- prep (fused): data->bf16, out0=adj copy, g2/BO, bi2 ----
__global__ __launch_bounds__(256) void k_prep_small(
        const float* __restrict__ data, unsigned short* __restrict__ dataB,
        const float* __restrict__ adj,  float* __restrict__ out0,
        const float* __restrict__ neurons, const float* __restrict__ w_out,
        const float* __restrict__ b_out, float* __restrict__ g2, float* __restrict__ BO,
        const float* __restrict__ b_in, float* __restrict__ bi2)
{
    const int b = blockIdx.x, tid = threadIdx.x;
    if (b < 1024) {                       // data f32 -> bf16 (262144 float4)
        int i = b * 256 + tid;
        float4 v = reinterpret_cast<const float4*>(data)[i];
        ushort4 o = make_ushort4(f2bf(v.x), f2bf(v.y), f2bf(v.z), f2bf(v.w));
        reinterpret_cast<ushort4*>(dataB)[i] = o;
    } else if (b < 1088) {                // out0 = adj (16384 float4)
        int i = (b - 1024) * 256 + tid;
        reinterpret_cast<float4*>(out0)[i] = reinterpret_cast<const float4*>(adj)[i];
    } else if (b < 1152) {                // g2[j] = 2*neurons[h,c]*w_out[j]; BO[c]=b_out[c]+sum_h g
        int j = (b - 1088) * 256 + tid;
        int c = j >> 6, h = j & 63;
        float gv = neurons[h * NV + c] * w_out[j];
        g2[j] = 2.0f * gv;
        float s = gv;
        s += __shfl_xor(s, 1);  s += __shfl_xor(s, 2);  s += __shfl_xor(s, 4);
        s += __shfl_xor(s, 8);  s += __shfl_xor(s, 16); s += __shfl_xor(s, 32);
        if ((tid & 63) == 0) BO[c] = b_out[c] + s;
    } else {                              // bi2 = K2 * b_in (4096 float4)
        int i = (b - 1152) * 256 + tid;
        float4 v = reinterpret_cast<const float4*>(b_in)[i];
        v.x *= K2F; v.y *= K2F; v.z *= K2F; v.w *= K2F;
        reinterpret_cast<float4*>(bi2)[i] = v;
    }
}

// ---- main: R4's all-register streaming loop (compile-proven), regridded.
// Wave = private 64-row A-strip, full K=256 resident (a[4][8], 128 VGPR).
// Block = 4 waves sharing ONE 8-channel group -> B stream L1-shared (32KB/ch).
// B global->reg, window 4 / prefetch distance 3 (R4-verified numerics).
// No LDS, no barriers. Grid 512 = 2 blocks/CU = 2 waves/SIMD.
// Swapped MFMA: D rows = h, D cols = m => h-sum is in-lane + 2 shfl.
__global__ __launch_bounds__(256, 2) void k_gemm_fused(
        const unsigned short* __restrict__ dataB,   // [4096][256] bf16
        const unsigned short* __restrict__ W2t,     // [16384][256] bf16
        const float* __restrict__ g2,               // [16384] 2*g
        const float* __restrict__ bi2,              // [16384] K2*b_in
        const float* __restrict__ BO,               // [256]  b_out + sum_h g
        float* __restrict__ out1)                   // [4096][256]
{
    const int tid  = threadIdx.x;
    const int w    = tid >> 6, lane = tid & 63;
    const int lq   = lane >> 4, lr = lane & 15;
    // grid 512 = 8 XCD x (4 ch-groups x 16 m-blocks): per XCD B-slice
    // 4x8x32KB = 1MB + A 2MB -> L2-resident.
    const int bid   = (int)blockIdx.x;
    const int xcd   = bid & 7, idx = bid >> 3;
    const int chgrp = xcd * 4 + (idx & 3);          // 0..31
    const int mblk  = idx >> 2;                     // 0..15
    const int m0    = mblk * 256 + w * 64;
    const int cbase = chgrp * 8;                    // 8 channels per block

    const s8v* Ab = (const s8v*)dataB;              // 16B units: row*32 + ks*4 + lq
    const s8v* Bb = (const s8v*)W2t;                // 16B units: col*32 + ks*4 + lq

    // A fragments, full K resident: lane lr = m-local row, lq = k-quarter
    s8v a[4][8];
#pragma unroll
    for (int mi = 0; mi < 4; ++mi)
#pragma unroll
        for (int ks = 0; ks < 8; ++ks)
            a[mi][ks] = Ab[(unsigned)(m0 + mi * 16 + lr) * 32u + ks * 4 + lq];

    // B prefetch window: 4 rotating slots of 4 fragments (hf = h-frag)
    s8v win[4][4];
#pragma unroll
    for (int j = 0; j < 3; ++j)                     // preload steps 0,1,2 of ch 0
#pragma unroll
        for (int hf = 0; hf < 4; ++hf)
            win[j][hf] = Bb[(unsigned)(cbase * 64 + hf * 16 + lr) * 32u + j * 4 + lq];

    for (int ch = 0; ch < 8; ++ch) {
        const int c = cbase + ch;

        // epilogue operands (issued early; consumed ~700 cyc later)
        float4 g2v[4], bi2v[4];
#pragma unroll
        for (int hf = 0; hf < 4; ++hf) {
            g2v[hf]  = *(const float4*)&g2 [c * 64 + hf * 16 + lq * 4];
            bi2v[hf] = *(const float4*)&bi2[c * 64 + hf * 16 + lq * 4];
        }
        const float BOv = BO[c];

        f4v acc[4][4];
#pragma unroll
        for (int kk = 0; kk < 8; ++kk) {
            // prefetch step kk+3 into slot (kk+3)&3 (wraps into next channel;
            // last channel's overrun reads land in ws scratch past W2t (g2
            // region) and are never consumed)
            {
                const int kk2 = (kk + 3) & 7;
                const int c2  = c + ((kk + 3) >> 3);
#pragma unroll
                for (int hf = 0; hf < 4; ++hf)
                    win[(kk + 3) & 3][hf] =
                        Bb[(unsigned)(c2 * 64 + hf * 16 + lr) * 32u + kk2 * 4 + lq];
            }
            // consume slot kk&3 (8 % 4 == 0 -> phase-aligned across channels)
#pragma unroll
            for (int mi = 0; mi < 4; ++mi)
#pragma unroll
                for (int hf = 0; hf < 4; ++hf) {
                    f4v cin = (kk == 0) ? (f4v){0.f, 0.f, 0.f, 0.f} : acc[mi][hf];
                    acc[mi][hf] = __builtin_amdgcn_mfma_f32_16x16x32_bf16(
                        win[kk & 3][hf], a[mi][kk], cin, 0, 0, 0);
                }
        }

        // Epilogue: per lane h = hf*16 + lq*4 + r ; m-local col = lr
        // out[m,c] = BO[c] - sum_h g2[h] * rcp(1 + exp2(K2*pre + bi2[h]))
        float s0, s1, s2, s3;
#define EPI_TERM(T, GC, BC, RR)                                                \
        { float mm = __builtin_fmaf(acc[mi][hf][RR], K2F, (BC));               \
          float e  = __builtin_amdgcn_exp2f(mm);                               \
          (T) = __builtin_fmaf((GC), __builtin_amdgcn_rcpf(e + 1.0f), (T)); }
#define EPI_MI(T)                                                              \
        { float t = 0.f;                                                       \
          _Pragma("unroll")                                                    \
          for (int hf = 0; hf < 4; ++hf) {                                     \
              EPI_TERM(t, g2v[hf].x, bi2v[hf].x, 0);                           \
              EPI_TERM(t, g2v[hf].y, bi2v[hf].y, 1);                           \
              EPI_TERM(t, g2v[hf].z, bi2v[hf].z, 2);                           \
              EPI_TERM(t, g2v[hf].w, bi2v[hf].w, 3);                           \
          }                                                                    \
          t += __shfl_xor(t, 16);                                              \
          t += __shfl_xor(t, 32);                                              \
          (T) = t; }
        { const int mi = 0; EPI_MI(s0); }
        { const int mi = 1; EPI_MI(s1); }
        { const int mi = 2; EPI_MI(s2); }
        { const int mi = 3; EPI_MI(s3); }
#undef EPI_MI
#undef EPI_TERM
        float v = lane < 16 ? s0 : (lane < 32 ? s1 : (lane < 48 ? s2 : s3));
        out1[(unsigned)(m0 + lane) * NV + c] = BOv - v;
    }
}

extern "C" void kernel_launch(void* const* d_in, const int* in_sizes, int n_in,
                              void* d_out, int out_size, void* d_ws, size_t ws_size,
                              hipStream_t stream) {
    const float* data    = (const float*)d_in[0];
    const float* adj     = (const float*)d_in[1];
    const float* neurons = (const float*)d_in[2];
    const float* w_in    = (const float*)d_in[3];
    const float* b_in    = (const float*)d_in[4];
    const float* w_out   = (const float*)d_in[5];
    const float* b_out   = (const float*)d_in[6];

    float* out0 = (float*)d_out;
    float* out1 = out0 + NV * NV;

    unsigned short* dataB = (unsigned short*)d_ws;                       // 2 MiB
    unsigned short* W2t   = (unsigned short*)((char*)d_ws + 2097152);    // 8 MiB
    float*          g2    = (float*)((char*)d_ws + 10485760);            // 64 KiB
    float*          bi2   = (float*)((char*)d_ws + 10551296);            // 64 KiB
    float*          BO    = (float*)((char*)d_ws + 10616832);            // 1 KiB

    hipLaunchKernelGGL(k_prep_w2t,   dim3(1024), dim3(256), 0, stream, adj, w_in, W2t);
    hipLaunchKernelGGL(k_prep_small, dim3(1168), dim3(256), 0, stream,
                       data, dataB, adj, out0, neurons, w_out, b_out, g2, BO, b_in, bi2);
    hipLaunchKernelGGL(k_gemm_fused, dim3(512), dim3(256), 0, stream,
                       dataB, W2t, g2, bi2, BO, out1);
}

// Round 8
// 62.328 us; speedup vs baseline: 2.4892x; 1.6791x over previous
//
#include <hip/hip_runtime.h>
#include <hip/hip_bf16.h>

// Sizes (fixed by the problem)
#define NS   4096      // samples
#define NV   256       // variables/channels
#define NHID 64        // hidden
#define K2F  2.8853900817779268f   // 2*log2(e)

typedef short s8v __attribute__((ext_vector_type(8)));
typedef float f4v __attribute__((ext_vector_type(4)));

typedef __attribute__((address_space(1))) const unsigned int GU;
typedef __attribute__((address_space(3))) unsigned int LU;

__device__ __forceinline__ void gload16(const void* gp, void* lp) {
    __builtin_amdgcn_global_load_lds((GU*)gp, (LU*)lp, 16, 0, 0);
}

__device__ __forceinline__ unsigned short f2bf(float x) {
    __hip_bfloat16 h = __float2bfloat16(x);
    return *reinterpret_cast<unsigned short*>(&h);
}

// ---- prep: W2t[col][k] = adj[k,c] * w_in[c, k-(k>c), h],  col = c*64+h ----
__global__ __launch_bounds__(256) void k_prep_w2t(const float* __restrict__ adj,
                                                  const float* __restrict__ w_in,
                                                  unsigned short* __restrict__ W2t) {
    __shared__ float t[64][65];
    int c  = blockIdx.x >> 2;
    int k0 = (blockIdx.x & 3) * 64;
    int tid = threadIdx.x;
#pragma unroll
    for (int i = 0; i < 16; ++i) {
        int lin = i * 256 + tid;
        int kr = lin >> 6, h = lin & 63;
        int k = k0 + kr;
        float v = 0.0f;
        if (k != c) {
            int m = k - (k > c ? 1 : 0);
            v = adj[k * NV + c] * w_in[((size_t)c * 255 + m) * 64 + h];
        }
        t[kr][h] = v;
    }
    __syncthreads();
#pragma unroll
    for (int i = 0; i < 16; ++i) {
        int lin = i * 256 + tid;
        int h = lin >> 6, kr = lin & 63;
        W2t[((size_t)(c * 64 + h)) * NV + k0 + kr] = f2bf(t[kr][h]);
    }
}

// ---- prep (fused): data->bf16, out0=adj copy, g2/BO, bi2 ----
__global__ __launch_bounds__(256) void k_prep_small(
        const float* __restrict__ data, unsigned short* __restrict__ dataB,
        const float* __restrict__ adj,  float* __restrict__ out0,
        const float* __restrict__ neurons, const float* __restrict__ w_out,
        const float* __restrict__ b_out, float* __restrict__ g2, float* __restrict__ BO,
        const float* __restrict__ b_in, float* __restrict__ bi2)
{
    const int b = blockIdx.x, tid = threadIdx.x;
    if (b < 1024) {                       // data f32 -> bf16 (262144 float4)
        int i = b * 256 + tid;
        float4 v = reinterpret_cast<const float4*>(data)[i];
        ushort4 o = make_ushort4(f2bf(v.x), f2bf(v.y), f2bf(v.z), f2bf(v.w));
        reinterpret_cast<ushort4*>(dataB)[i] = o;
    } else if (b < 1088) {                // out0 = adj (16384 float4)
        int i = (b - 1024) * 256 + tid;
        reinterpret_cast<float4*>(out0)[i] = reinterpret_cast<const float4*>(adj)[i];
    } else if (b < 1152) {                // g2[j] = 2*neurons[h,c]*w_out[j]; BO[c]=b_out[c]+sum_h g
        int j = (b - 1088) * 256 + tid;
        int c = j >> 6, h = j & 63;
        float gv = neurons[h * NV + c] * w_out[j];
        g2[j] = 2.0f * gv;
        float s = gv;
        s += __shfl_xor(s, 1);  s += __shfl_xor(s, 2);  s += __shfl_xor(s, 4);
        s += __shfl_xor(s, 8);  s += __shfl_xor(s, 16); s += __shfl_xor(s, 32);
        if ((tid & 63) == 0) BO[c] = b_out[c] + s;
    } else {                              // bi2 = K2 * b_in (4096 float4)
        int i = (b - 1152) * 256 + tid;
        float4 v = reinterpret_cast<const float4*>(b_in)[i];
        v.x *= K2F; v.y *= K2F; v.z *= K2F; v.w *= K2F;
        reinterpret_cast<float4*>(bi2)[i] = v;
    }
}

// ---- main: R1's proven 128x128/BK64/4-wave LDS skeleton, with
//  (1) swapped MFMA operands: acc = mfma(W_frag, data_frag) -> D rows = h,
//      D cols = m  => h-reduction is in-lane + 2 shfl (no shfl storm),
//  (2) lean epilogue (exp2/rcp form),
//  (3) XCD-chunked block swizzle (R3-proven, FETCH 34->12.4 GB).
__global__ __launch_bounds__(256, 3) void k_gemm_fused(
        const unsigned short* __restrict__ dataB,   // [4096][256] bf16
        const unsigned short* __restrict__ W2t,     // [16384][256] bf16
        const float* __restrict__ g2,               // [16384] 2*g
        const float* __restrict__ bi2,              // [16384] K2*b_in
        const float* __restrict__ BO,               // [256]  b_out + sum_h g
        float* __restrict__ out1)                   // [4096][256]
{
    __shared__ __align__(16) char lds[32768];       // A: [0,16K)  B: [16K,32K)
    const int tid  = threadIdx.x;
    const int w    = tid >> 6;
    const int lane = tid & 63;
    const int lq   = lane >> 4, lr = lane & 15;
    const int wr   = w >> 1, wc = w & 1;

    // XCD-chunked swizzle (R3-proven): 4096 blocks, 512/XCD.
    const int orig = (int)blockIdx.x;
    const int swz  = (orig & 7) * 512 + (orig >> 3);
    const int bm0  = (swz & 31) << 7;
    const int bn0  = (swz >> 5) << 7;

    f4v acc[4][4];
#pragma unroll
    for (int mi = 0; mi < 4; ++mi)
#pragma unroll
        for (int ni = 0; ni < 4; ++ni)
            acc[mi][ni] = (f4v){0.f, 0.f, 0.f, 0.f};

    // Staging offsets (R1-proven). LDS dest LINEAR (global_load_lds constraint);
    // XOR swizzle applied to GLOBAL source + again on ds_read (rule #21).
    unsigned int offA[4], offB[4], ldso[4];
#pragma unroll
    for (int t = 0; t < 4; ++t) {
        int o = w * 4096 + t * 1024 + lane * 16;    // linear byte offset in 16KB tile
        int row = o >> 7;                            // 128 B per row (64 bf16)
        int inner = (o & 127) ^ ((row & 7) << 4);    // inverse swizzle on source
        ldso[t] = (unsigned)(w * 4096 + t * 1024);   // wave-uniform LDS base
        offA[t] = (unsigned)(bm0 + row) * 512u + (unsigned)inner;
        offB[t] = (unsigned)(bn0 + row) * 512u + (unsigned)inner;
    }

    const char* dA = (const char*)dataB;
    const char* dB = (const char*)W2t;

    for (int kt = 0; kt < 4; ++kt) {
#pragma unroll
        for (int t = 0; t < 4; ++t)
            gload16(dA + (size_t)offA[t] + kt * 128, lds + ldso[t]);
#pragma unroll
        for (int t = 0; t < 4; ++t)
            gload16(dB + (size_t)offB[t] + kt * 128, lds + 16384 + ldso[t]);
        __syncthreads();   // compiler drains vmcnt before s_barrier

#pragma unroll
        for (int kk = 0; kk < 2; ++kk) {
            s8v afr[4], bfr[4];
#pragma unroll
            for (int mi = 0; mi < 4; ++mi) {
                int ml = wr * 64 + mi * 16 + lr;
                int inner = (kk * 64 + (lq << 4)) ^ ((ml & 7) << 4);
                afr[mi] = *reinterpret_cast<const s8v*>(lds + ml * 128 + inner);
            }
#pragma unroll
            for (int ni = 0; ni < 4; ++ni) {
                int nl = wc * 64 + ni * 16 + lr;
                int inner = (kk * 64 + (lq << 4)) ^ ((nl & 7) << 4);
                bfr[ni] = *reinterpret_cast<const s8v*>(lds + 16384 + nl * 128 + inner);
            }
            __builtin_amdgcn_s_setprio(1);
#pragma unroll
            for (int mi = 0; mi < 4; ++mi)
#pragma unroll
                for (int ni = 0; ni < 4; ++ni)
                    acc[mi][ni] = __builtin_amdgcn_mfma_f32_16x16x32_bf16(
                        bfr[ni], afr[mi], acc[mi][ni], 0, 0, 0);   // SWAPPED: W first
            __builtin_amdgcn_s_setprio(0);
        }
        __syncthreads();
    }

    // Epilogue (R4-validated layout): lane holds D[h-local = ni*16+lq*4+j][m-local = lr].
    // out[m,c] = BO[c] - sum_h g2[h] * rcp(1 + exp2(K2*pre + bi2[h]))
    const int cidx = (bn0 >> 6) + wc;               // this wave's channel c
    float4 g2v[4], bi2v[4];
#pragma unroll
    for (int ni = 0; ni < 4; ++ni) {
        int base = cidx * 64 + ni * 16 + lq * 4;
        g2v[ni]  = *(const float4*)&g2 [base];
        bi2v[ni] = *(const float4*)&bi2[base];
    }
    const float BOv = BO[cidx];

    float s0, s1, s2, s3;
#define EPI_TERM(T, GC, BC, RR)                                                \
    { float mm = __builtin_fmaf(acc[mi][ni][RR], K2F, (BC));                   \
      float e  = __builtin_amdgcn_exp2f(mm);                                   \
      (T) = __builtin_fmaf((GC), __builtin_amdgcn_rcpf(e + 1.0f), (T)); }
#define EPI_MI(T)                                                              \
    { float t = 0.f;                                                           \
      _Pragma("unroll")                                                        \
      for (int ni = 0; ni < 4; ++ni) {                                         \
          EPI_TERM(t, g2v[ni].x, bi2v[ni].x, 0);                               \
          EPI_TERM(t, g2v[ni].y, bi2v[ni].y, 1);                               \
          EPI_TERM(t, g2v[ni].z, bi2v[ni].z, 2);                               \
          EPI_TERM(t, g2v[ni].w, bi2v[ni].w, 3);                               \
      }                                                                        \
      t += __shfl_xor(t, 16);                                                  \
      t += __shfl_xor(t, 32);                                                  \
      (T) = t; }
    { const int mi = 0; EPI_MI(s0); }
    { const int mi = 1; EPI_MI(s1); }
    { const int mi = 2; EPI_MI(s2); }
    { const int mi = 3; EPI_MI(s3); }
#undef EPI_MI
#undef EPI_TERM
    // lane = mi*16 + lr after selection: one 64-row column store per wave
    float v = lane < 16 ? s0 : (lane < 32 ? s1 : (lane < 48 ? s2 : s3));
    out1[(unsigned)(bm0 + wr * 64 + lane) * NV + cidx] = BOv - v;
}

extern "C" void kernel_launch(void* const* d_in, const int* in_sizes, int n_in,
                              void* d_out, int out_size, void* d_ws, size_t ws_size,
                              hipStream_t stream) {
    const float* data    = (const float*)d_in[0];
    const float* adj     = (const float*)d_in[1];
    const float* neurons = (const float*)d_in[2];
    const float* w_in    = (const float*)d_in[3];
    const float* b_in    = (const float*)d_in[4];
    const float* w_out   = (const float*)d_in[5];
    const float* b_out   = (const float*)d_in[6];

    float* out0 = (float*)d_out;
    float* out1 = out0 + NV * NV;

    unsigned short* dataB = (unsigned short*)d_ws;                       // 2 MiB
    unsigned short* W2t   = (unsigned short*)((char*)d_ws + 2097152);    // 8 MiB
    float*          g2    = (float*)((char*)d_ws + 10485760);            // 64 KiB
    float*          bi2   = (float*)((char*)d_ws + 10551296);            // 64 KiB
    float*          BO    = (float*)((char*)d_ws + 10616832);            // 1 KiB

    hipLaunchKernelGGL(k_prep_w2t,   dim3(1024), dim3(256), 0, stream, adj, w_in, W2t);
    hipLaunchKernelGGL(k_prep_small, dim3(1168), dim3(256), 0, stream,
                       data, dataB, adj, out0, neurons, w_out, b_out, g2, BO, b_in, bi2);
    hipLaunchKernelGGL(k_gemm_fused, dim3(4096), dim3(256), 0, stream,
                       dataB, W2t, g2, bi2, BO, out1);
}

// Round 9
// 60.015 us; speedup vs baseline: 2.5852x; 1.0385x over previous
//
#include <hip/hip_runtime.h>
#include <hip/hip_bf16.h>

// Sizes (fixed by the problem)
#define NS   4096      // samples
#define NV   256       // variables/channels
#define NHID 64        // hidden
#define K2F  2.8853900817779268f   // 2*log2(e)

typedef short s8v __attribute__((ext_vector_type(8)));
typedef float f4v __attribute__((ext_vector_type(4)));

typedef __attribute__((address_space(1))) const unsigned int GU;
typedef __attribute__((address_space(3))) unsigned int LU;

__device__ __forceinline__ void gload16(const void* gp, void* lp) {
    __builtin_amdgcn_global_load_lds((GU*)gp, (LU*)lp, 16, 0, 0);
}

__device__ __forceinline__ unsigned short f2bf(float x) {
    __hip_bfloat16 h = __float2bfloat16(x);
    return *reinterpret_cast<unsigned short*>(&h);
}

// ---- merged prep: blocks [0,1024): W2t ; [1024,2192): data/out0/g2/BO/bi2 ----
// W2t[col][k] = adj[k,c] * w_in[c, k-(k>c), h],  col = c*64+h
__global__ __launch_bounds__(256) void k_prep_all(
        const float* __restrict__ adj, const float* __restrict__ w_in,
        unsigned short* __restrict__ W2t,
        const float* __restrict__ data, unsigned short* __restrict__ dataB,
        float* __restrict__ out0,
        const float* __restrict__ neurons, const float* __restrict__ w_out,
        const float* __restrict__ b_out, float* __restrict__ g2, float* __restrict__ BO,
        const float* __restrict__ b_in, float* __restrict__ bi2)
{
    __shared__ float t[64][65];
    const int blk = blockIdx.x, tid = threadIdx.x;
    if (blk < 1024) {
        int c  = blk >> 2;
        int k0 = (blk & 3) * 64;
#pragma unroll
        for (int i = 0; i < 16; ++i) {
            int lin = i * 256 + tid;
            int kr = lin >> 6, h = lin & 63;
            int k = k0 + kr;
            float v = 0.0f;
            if (k != c) {
                int m = k - (k > c ? 1 : 0);
                v = adj[k * NV + c] * w_in[((size_t)c * 255 + m) * 64 + h];
            }
            t[kr][h] = v;
        }
        __syncthreads();
#pragma unroll
        for (int i = 0; i < 16; ++i) {
            int lin = i * 256 + tid;
            int h = lin >> 6, kr = lin & 63;
            W2t[((size_t)(c * 64 + h)) * NV + k0 + kr] = f2bf(t[kr][h]);
        }
        return;
    }
    const int b = blk - 1024;
    if (b < 1024) {                       // data f32 -> bf16 (262144 float4)
        int i = b * 256 + tid;
        float4 v = reinterpret_cast<const float4*>(data)[i];
        ushort4 o = make_ushort4(f2bf(v.x), f2bf(v.y), f2bf(v.z), f2bf(v.w));
        reinterpret_cast<ushort4*>(dataB)[i] = o;
    } else if (b < 1088) {                // out0 = adj (16384 float4)
        int i = (b - 1024) * 256 + tid;
        reinterpret_cast<float4*>(out0)[i] = reinterpret_cast<const float4*>(adj)[i];
    } else if (b < 1152) {                // g2[j]=2*neurons[h,c]*w_out[j]; BO[c]=b_out[c]+sum_h g
        int j = (b - 1088) * 256 + tid;
        int c = j >> 6, h = j & 63;
        float gv = neurons[h * NV + c] * w_out[j];
        g2[j] = 2.0f * gv;
        float s = gv;
        s += __shfl_xor(s, 1);  s += __shfl_xor(s, 2);  s += __shfl_xor(s, 4);
        s += __shfl_xor(s, 8);  s += __shfl_xor(s, 16); s += __shfl_xor(s, 32);
        if ((tid & 63) == 0) BO[c] = b_out[c] + s;
    } else {                              // bi2 = K2 * b_in (4096 float4)
        int i = (b - 1152) * 256 + tid;
        float4 v = reinterpret_cast<const float4*>(b_in)[i];
        v.x *= K2F; v.y *= K2F; v.z *= K2F; v.w *= K2F;
        reinterpret_cast<float4*>(bi2)[i] = v;
    }
}

// ---- main: 128x128 tile, BK=32, 8 K-steps, 3-buffer LDS (48KB), 2-deep
// counted-vmcnt pipeline, ONE barrier per K-step, no mid-loop drains.
// BK=32 makes every MFMA fragment read a contiguous 1KB LDS block (16 rows
// x 64B) -> bank-balanced, NO swizzle needed on stage or read.
// Swapped MFMA (R8-validated): D rows = h, D cols = m; lean exp2 epilogue.
__global__ __launch_bounds__(256, 3) void k_gemm_fused(
        const unsigned short* __restrict__ dataB,   // [4096][256] bf16
        const unsigned short* __restrict__ W2t,     // [16384][256] bf16
        const float* __restrict__ g2,               // [16384] 2*g
        const float* __restrict__ bi2,              // [16384] K2*b_in
        const float* __restrict__ BO,               // [256]  b_out + sum_h g
        float* __restrict__ out1)                   // [4096][256]
{
    __shared__ __align__(16) char lds[49152];       // 3 x (A 8K | B 8K)
    const int tid  = threadIdx.x;
    const int w    = tid >> 6;
    const int lane = tid & 63;
    const int lq   = lane >> 4, lr = lane & 15;
    const int wr   = w >> 1, wc = w & 1;

    // XCD-chunked swizzle (R3/R8-proven): 4096 blocks, 512/XCD.
    const int orig = (int)blockIdx.x;
    const int swz  = (orig & 7) * 512 + (orig >> 3);
    const int bm0  = (swz & 31) << 7;
    const int bn0  = (swz >> 5) << 7;

    f4v acc[4][4];
#pragma unroll
    for (int mi = 0; mi < 4; ++mi)
#pragma unroll
        for (int ni = 0; ni < 4; ++ni)
            acc[mi][ni] = (f4v){0.f, 0.f, 0.f, 0.f};

    // Staging bases. Per stage (BK=32): A 128x32 bf16 = 8KB (rounds 0-1),
    // B 8KB (rounds 2-3); 256 thr x 16B = 4KB/round. Linear LDS dest.
    const char* dA = (const char*)dataB;
    const char* dB = (const char*)W2t;
    const int rowt = tid >> 2;                       // 0..63
    const int colb = (tid & 3) * 16;                 // byte within 64B row
    const char* srcA = dA + (size_t)(bm0 + rowt) * 512 + colb;
    const char* srcB = dB + (size_t)(bn0 + rowt) * 512 + colb;
    const unsigned ldst = (unsigned)(rowt * 64 + colb);  // == tid*16

#define STAGE(KT, BUFO)                                                        \
    do {                                                                       \
        gload16(srcA + (KT) * 64,         lds + (BUFO) + ldst);                \
        gload16(srcA + 32768 + (KT) * 64, lds + (BUFO) + 4096 + ldst);         \
        gload16(srcB + (KT) * 64,         lds + (BUFO) + 8192 + ldst);         \
        gload16(srcB + 32768 + (KT) * 64, lds + (BUFO) + 12288 + ldst);        \
    } while (0)

    // Prologue: 2 stages in flight.
    STAGE(0, 0);
    STAGE(1, 16384);

#pragma unroll
    for (int kt = 0; kt < 8; ++kt) {
        const int bufo = (kt % 3) * 16384;
        if (kt < 7) { asm volatile("s_waitcnt vmcnt(4)" ::: "memory"); }
        else        { asm volatile("s_waitcnt vmcnt(0)" ::: "memory"); }
        __builtin_amdgcn_sched_barrier(0);
        __builtin_amdgcn_s_barrier();                // stage kt visible to all
        __builtin_amdgcn_sched_barrier(0);
        // buffer (kt+2)%3 == (kt-1)%3 was last read at iter kt-1; the barrier
        // above proves every wave finished those reads -> safe to overwrite.
        if (kt < 6) STAGE(kt + 2, ((kt + 2) % 3) * 16384);

        s8v afr[4], bfr[4];
#pragma unroll
        for (int mi = 0; mi < 4; ++mi) {
            int ml = wr * 64 + mi * 16 + lr;
            afr[mi] = *reinterpret_cast<const s8v*>(lds + bufo + ml * 64 + lq * 16);
        }
#pragma unroll
        for (int ni = 0; ni < 4; ++ni) {
            int nl = wc * 64 + ni * 16 + lr;
            bfr[ni] = *reinterpret_cast<const s8v*>(lds + bufo + 8192 + nl * 64 + lq * 16);
        }
        __builtin_amdgcn_s_setprio(1);
#pragma unroll
        for (int mi = 0; mi < 4; ++mi)
#pragma unroll
            for (int ni = 0; ni < 4; ++ni)
                acc[mi][ni] = __builtin_amdgcn_mfma_f32_16x16x32_bf16(
                    bfr[ni], afr[mi], acc[mi][ni], 0, 0, 0);   // SWAPPED: W first
        __builtin_amdgcn_s_setprio(0);
    }
#undef STAGE

    // Epilogue (R8-validated): lane holds D[h-local = ni*16+lq*4+j][m-local = lr].
    // out[m,c] = BO[c] - sum_h g2[h] * rcp(1 + exp2(K2*pre + bi2[h]))
    const int cidx = (bn0 >> 6) + wc;               // this wave's channel c
    float4 g2v[4], bi2v[4];
#pragma unroll
    for (int ni = 0; ni < 4; ++ni) {
        int base = cidx * 64 + ni * 16 + lq * 4;
        g2v[ni]  = *(const float4*)&g2 [base];
        bi2v[ni] = *(const float4*)&bi2[base];
    }
    const float BOv = BO[cidx];

    float s0, s1, s2, s3;
#define EPI_TERM(T, GC, BC, RR)                                                \
    { float mm = __builtin_fmaf(acc[mi][ni][RR], K2F, (BC));                   \
      float e  = __builtin_amdgcn_exp2f(mm);                                   \
      (T) = __builtin_fmaf((GC), __builtin_amdgcn_rcpf(e + 1.0f), (T)); }
#define EPI_MI(T)                                                              \
    { float t = 0.f;                                                           \
      _Pragma("unroll")                                                        \
      for (int ni = 0; ni < 4; ++ni) {                                         \
          EPI_TERM(t, g2v[ni].x, bi2v[ni].x, 0);                               \
          EPI_TERM(t, g2v[ni].y, bi2v[ni].y, 1);                               \
          EPI_TERM(t, g2v[ni].z, bi2v[ni].z, 2);                               \
          EPI_TERM(t, g2v[ni].w, bi2v[ni].w, 3);                               \
      }                                                                        \
      t += __shfl_xor(t, 16);                                                  \
      t += __shfl_xor(t, 32);                                                  \
      (T) = t; }
    { const int mi = 0; EPI_MI(s0); }
    { const int mi = 1; EPI_MI(s1); }
    { const int mi = 2; EPI_MI(s2); }
    { const int mi = 3; EPI_MI(s3); }
#undef EPI_MI
#undef EPI_TERM
    float v = lane < 16 ? s0 : (lane < 32 ? s1 : (lane < 48 ? s2 : s3));
    out1[(unsigned)(bm0 + wr * 64 + lane) * NV + cidx] = BOv - v;
}

extern "C" void kernel_launch(void* const* d_in, const int* in_sizes, int n_in,
                              void* d_out, int out_size, void* d_ws, size_t ws_size,
                              hipStream_t stream) {
    const float* data    = (const float*)d_in[0];
    const float* adj     = (const float*)d_in[1];
    const float* neurons = (const float*)d_in[2];
    const float* w_in    = (const float*)d_in[3];
    const float* b_in    = (const float*)d_in[4];
    const float* w_out   = (const float*)d_in[5];
    const float* b_out   = (const float*)d_in[6];

    float* out0 = (float*)d_out;
    float* out1 = out0 + NV * NV;

    unsigned short* dataB = (unsigned short*)d_ws;                       // 2 MiB
    unsigned short* W2t   = (unsigned short*)((char*)d_ws + 2097152);    // 8 MiB
    float*          g2    = (float*)((char*)d_ws + 10485760);            // 64 KiB
    float*          bi2   = (float*)((char*)d_ws + 10551296);            // 64 KiB
    float*          BO    = (float*)((char*)d_ws + 10616832);            // 1 KiB

    hipLaunchKernelGGL(k_prep_all, dim3(2192), dim3(256), 0, stream,
                       adj, w_in, W2t, data, dataB, out0,
                       neurons, w_out, b_out, g2, BO, b_in, bi2);
    hipLaunchKernelGGL(k_gemm_fused, dim3(4096), dim3(256), 0, stream,
                       dataB, W2t, g2, bi2, BO, out1);
}